// Round 7
// baseline (586.039 us; speedup 1.0000x reference)
//
#include <hip/hip_runtime.h>
#include <hip/hip_bf16.h>
#include <math.h>

#define N_NODES 100000
#define N_EDGES 1600000
#define NFEAT 512
#define NHID 128
#define NCLASS 40

// Bucketed edges: 64 dst nodes per bucket (BSH=6). Aggregation blocks
// counting-sort their bucket's edges in LDS (integer atomics only — round-3
// lesson: NO float atomics on the per-edge path), then accumulate in
// registers barrier-free (round-5 proven), MFMA gemm2 epilogue.
// Round-7: de-fused partition/gemm1 (round-6 fusion was a 143us regression);
// partition now does an in-LDS counting sort + grouped write-out to cut
// scatter write transactions ~2.5x.
#define BSH 6
#define BNODES (1 << BSH)                                  // 64
#define NBUCK ((N_NODES + BNODES - 1) / BNODES)            // 1563

// hist/partition: edges per block
#define PCHUNK 4096
#define PEPT 16
#define PNB ((N_EDGES + PCHUNK - 1) / PCHUNK)              // 391

// In-LDS edge staging capacity per bucket in aggs (mean 1024, sigma ~32;
// 1536=+16s; guarded by a correct global-scan fallback).
#define CAP 1536
#define KSTG 6   // CAP / 256

typedef short bf16x8 __attribute__((ext_vector_type(8)));
typedef float f32x4 __attribute__((ext_vector_type(4)));

static __device__ __forceinline__ unsigned short f32_to_bf16(float f) {
    unsigned int u = __float_as_uint(f);
    unsigned int r = u + 0x7FFFu + ((u >> 16) & 1u);   // RNE
    return (unsigned short)(r >> 16);
}
static __device__ __forceinline__ float bf16_to_f32(unsigned short h) {
    return __uint_as_float(((unsigned int)h) << 16);
}

// ---------------------------------------------------------------------------
// Fused: bucket histogram (blocks [0,PNB)) + W1 transpose->bf16 + W2
// transpose->bf16 (zero-padded to 48 classes) in the tail blocks.
// ---------------------------------------------------------------------------
__global__ __launch_bounds__(256) void bucket_hist_transpose_kernel(
    const int* __restrict__ dst, int* __restrict__ histG,
    const float* __restrict__ W1, unsigned short* __restrict__ Wt,
    const float* __restrict__ W2, unsigned short* __restrict__ W2t, int E)
{
    const int blk = blockIdx.x;
    if (blk >= PNB + 256) {
        // W2t[c][k] = bf16(W2[k][c]) for c<40 else 0;  48*128 = 6144 elems
        int i = (blk - PNB - 256) * 256 + threadIdx.x;
        if (i < 48 * 128) {
            int c = i >> 7;
            int k = i & 127;
            W2t[i] = (c < NCLASS) ? f32_to_bf16(W2[k * NCLASS + c]) : 0;
        }
        return;
    }
    if (blk >= PNB) {
        int tid2 = (blk - PNB) * 256 + threadIdx.x;    // 65536 total
        int n = tid2 >> 9;
        int k = tid2 & 511;
        Wt[tid2] = f32_to_bf16(W1[k * NHID + n]);
        return;
    }
    __shared__ int hl[NBUCK];
    const int t = threadIdx.x;
    for (int j = t; j < NBUCK; j += 256) hl[j] = 0;
    __syncthreads();
    const int c0 = blk * PCHUNK;
    #pragma unroll
    for (int i = 0; i < PEPT; i++) {
        int e = c0 + t + i * 256;
        if (e < E) atomicAdd(&hl[dst[e] >> BSH], 1);
    }
    __syncthreads();
    for (int j = t; j < NBUCK; j += 256) {
        int c = hl[j];
        if (c) atomicAdd(&histG[j * 16], c);   // 64B-padded counters
    }
}

// ---------------------------------------------------------------------------
// Bucket scan: 1563 counts (2 per thread) -> exclusive bofs[NBUCK+1] +
// bcursor init.
// ---------------------------------------------------------------------------
__global__ __launch_bounds__(1024) void bucket_scan_kernel(
    const int* __restrict__ histG, int* __restrict__ bofs,
    int* __restrict__ bcursor)
{
    __shared__ int sh[1024];
    const int t = threadIdx.x;
    const int i0 = 2 * t, i1 = 2 * t + 1;
    int v0 = (i0 < NBUCK) ? histG[i0 * 16] : 0;
    int v1 = (i1 < NBUCK) ? histG[i1 * 16] : 0;
    int s = v0 + v1;
    sh[t] = s;
    __syncthreads();
    #pragma unroll
    for (int off = 1; off < 1024; off <<= 1) {
        int u = (t >= off) ? sh[t - off] : 0;
        __syncthreads();
        sh[t] += u;
        __syncthreads();
    }
    int base = sh[t] - s;
    if (i0 < NBUCK) { bofs[i0] = base;      bcursor[i0] = base; }
    if (i1 < NBUCK) { bofs[i1] = base + v0; bcursor[i1] = base + v0; }
    if (t == 1023) bofs[NBUCK] = sh[1023];
}

// ---------------------------------------------------------------------------
// Partition with grouped write-out: per block, counting-sort 4096 records in
// LDS by bucket, record each record's global slot (gbase[j] + rank-in-run),
// then write linearly: consecutive lanes -> mostly-consecutive global
// addresses (~2.5x fewer scatter transactions than per-edge random).
// Pack: x = src | (dst & 63) << 17  (src < 2^17), y = weight bits.
// ---------------------------------------------------------------------------
__global__ __launch_bounds__(256) void partition_kernel(
    const int* __restrict__ src, const int* __restrict__ dstp,
    const float* __restrict__ w, int* __restrict__ bcursor,
    int2* __restrict__ sortedA, int E)
{
    __shared__ int lcur[NBUCK];                   // counts, then cursors
    __shared__ int lofs[NBUCK];
    __shared__ int gbase[NBUCK];
    __shared__ int psum[256];
    __shared__ __align__(16) int2 ebuf[PCHUNK];   // 32,768 B
    __shared__ int gpos[PCHUNK];                  // 16,384 B

    const int t = threadIdx.x;
    const int c0 = blockIdx.x * PCHUNK;
    const int cnt = min(PCHUNK, E - c0);

    for (int j = t; j < NBUCK; j += 256) lcur[j] = 0;
    __syncthreads();

    // load + per-block bucket count
    int  myb[PEPT];
    int2 myv[PEPT];
    #pragma unroll
    for (int i = 0; i < PEPT; i++) {
        int e = c0 + t + i * 256;
        if (e < E) {
            int d = dstp[e];
            myb[i] = d >> BSH;
            myv[i] = make_int2(src[e] | ((d & (BNODES - 1)) << 17),
                               __float_as_int(w[e]));
            atomicAdd(&lcur[myb[i]], 1);
        } else {
            myb[i] = -1;
        }
    }
    __syncthreads();

    // exclusive scan over NBUCK counts: thread t owns buckets [7t, 7t+7)
    int c[7];
    int s = 0;
    #pragma unroll
    for (int k = 0; k < 7; k++) {
        int j = t * 7 + k;
        c[k] = (j < NBUCK) ? lcur[j] : 0;
        s += c[k];
    }
    psum[t] = s;
    __syncthreads();
    #pragma unroll
    for (int off = 1; off < 256; off <<= 1) {
        int u = (t >= off) ? psum[t - off] : 0;
        __syncthreads();
        psum[t] += u;
        __syncthreads();
    }
    int run = psum[t] - s;
    #pragma unroll
    for (int k = 0; k < 7; k++) {
        int j = t * 7 + k;
        if (j < NBUCK) {
            lofs[j] = run;
            lcur[j] = run;                         // becomes scatter cursor
            gbase[j] = c[k] ? atomicAdd(&bcursor[j], c[k]) : 0;
            run += c[k];
        }
    }
    __syncthreads();

    // scatter into LDS (bucket-sorted) + compute exact global slot
    #pragma unroll
    for (int i = 0; i < PEPT; i++) {
        if (myb[i] >= 0) {
            int p = atomicAdd(&lcur[myb[i]], 1);
            ebuf[p] = myv[i];
            gpos[p] = gbase[myb[i]] + (p - lofs[myb[i]]);
        }
    }
    __syncthreads();

    // grouped write-out
    for (int i = t; i < cnt; i += 256)
        sortedA[gpos[i]] = ebuf[i];
}

// ---------------------------------------------------------------------------
// GEMM1 (bf16 MFMA): h1b[M,128](bf16) = features[M,512](fp32) @ W1
// ---------------------------------------------------------------------------
__global__ __launch_bounds__(256) void gemm1_mfma_kernel(
    const float* __restrict__ A,            // [M,512]
    const unsigned short* __restrict__ Wt,  // [128][512] bf16, Wt[n][k]
    unsigned short* __restrict__ h1b,       // [M,128] bf16
    int M)
{
    __shared__ unsigned short cstage[4][32 * 130];   // per-wave 32x128 (+2 pad)

    const int tid = threadIdx.x;
    const int w4 = tid >> 6;
    const int lane = tid & 63;
    const int lr = lane & 15;
    const int quad = lane >> 4;
    const int m0 = blockIdx.x * 128 + w4 * 32;

    f32x4 acc[2][8];
    #pragma unroll
    for (int rt = 0; rt < 2; rt++)
        #pragma unroll
        for (int ct = 0; ct < 8; ct++)
            acc[rt][ct] = (f32x4){0.f, 0.f, 0.f, 0.f};

    int r0 = m0 + lr;
    int r1 = m0 + 16 + lr;
    int r0c = r0 < M ? r0 : M - 1;
    int r1c = r1 < M ? r1 : M - 1;
    const float* a0p = A + (size_t)r0c * NFEAT + quad * 8;
    const float* a1p = A + (size_t)r1c * NFEAT + quad * 8;
    const unsigned short* bp = Wt + (size_t)lr * NFEAT + quad * 8;

    #pragma unroll 2
    for (int k0 = 0; k0 < NFEAT; k0 += 32) {
        float4 a0a = *(const float4*)(a0p + k0);
        float4 a0b = *(const float4*)(a0p + k0 + 4);
        float4 a1a = *(const float4*)(a1p + k0);
        float4 a1b = *(const float4*)(a1p + k0 + 4);

        bf16x8 fb[8];
        #pragma unroll
        for (int ct = 0; ct < 8; ct++)
            fb[ct] = *(const bf16x8*)(bp + (size_t)ct * 16 * NFEAT + k0);

        bf16x8 fa0, fa1;
        fa0[0] = (short)f32_to_bf16(a0a.x); fa0[1] = (short)f32_to_bf16(a0a.y);
        fa0[2] = (short)f32_to_bf16(a0a.z); fa0[3] = (short)f32_to_bf16(a0a.w);
        fa0[4] = (short)f32_to_bf16(a0b.x); fa0[5] = (short)f32_to_bf16(a0b.y);
        fa0[6] = (short)f32_to_bf16(a0b.z); fa0[7] = (short)f32_to_bf16(a0b.w);
        fa1[0] = (short)f32_to_bf16(a1a.x); fa1[1] = (short)f32_to_bf16(a1a.y);
        fa1[2] = (short)f32_to_bf16(a1a.z); fa1[3] = (short)f32_to_bf16(a1a.w);
        fa1[4] = (short)f32_to_bf16(a1b.x); fa1[5] = (short)f32_to_bf16(a1b.y);
        fa1[6] = (short)f32_to_bf16(a1b.z); fa1[7] = (short)f32_to_bf16(a1b.w);

        #pragma unroll
        for (int ct = 0; ct < 8; ct++) {
            acc[0][ct] = __builtin_amdgcn_mfma_f32_16x16x32_bf16(fa0, fb[ct], acc[0][ct], 0, 0, 0);
            acc[1][ct] = __builtin_amdgcn_mfma_f32_16x16x32_bf16(fa1, fb[ct], acc[1][ct], 0, 0, 0);
        }
    }

    unsigned short* st = cstage[w4];
    #pragma unroll
    for (int rt = 0; rt < 2; rt++)
        #pragma unroll
        for (int ct = 0; ct < 8; ct++)
            #pragma unroll
            for (int i = 0; i < 4; i++) {
                int row = rt * 16 + quad * 4 + i;
                int col = ct * 16 + lr;
                st[row * 130 + col] = f32_to_bf16(acc[rt][ct][i]);
            }

    #pragma unroll
    for (int g = 0; g < 8; g++) {
        int row = g * 4 + (lane >> 4);          // 0..31
        int c8 = lane & 15;                      // 16B chunk index
        const unsigned short* rp = &st[row * 130 + c8 * 8];
        uint4 v = *(const uint4*)rp;
        int gr = m0 + row;
        if (gr < M)
            *(uint4*)&h1b[(size_t)gr * NHID + c8 * 8] = v;
    }
}

// ---------------------------------------------------------------------------
// agg1 + bias + relu + gemm2: one block per 64-node bucket.
// 1) in-LDS counting sort (integer atomics only).
// 2) barrier-free accumulate: 8 groups x 32 lanes; group g owns nodes
//    [8g,8g+8) back-to-back; rows -> bf16 -> xs[64][136].
// 3) one barrier, MFMA gemm2: h2[64x40] = xs @ W2t (12 mfma/wave).
// ---------------------------------------------------------------------------
__global__ __launch_bounds__(256) void agg1_gemm2_kernel(
    const int2* __restrict__ sortedA, const int* __restrict__ bofs,
    const unsigned short* __restrict__ h1b, const float* __restrict__ b1,
    const unsigned short* __restrict__ W2t, float* __restrict__ h2, int N)
{
    __shared__ __align__(16) int2 ebuf[CAP];                  // 12,288 B
    __shared__ __align__(16) unsigned short xs[64][136];      // 17,408 B
    __shared__ __align__(16) unsigned short wt2s[48 * 136];   // 13,056 B
    __shared__ int ncnt[BNODES];
    __shared__ int nofs[BNODES];
    __shared__ int ncur[BNODES];
    __shared__ int sc[BNODES];
    __shared__ float b1s[128];

    const int tid = threadIdx.x;
    const int b = blockIdx.x;
    const int node0 = b << BSH;
    const int nn = min(BNODES, N - node0);
    const int beg = bofs[b];
    const int end = bofs[b + 1];
    const int cnt = end - beg;
    const bool fits = (cnt <= CAP);

    // stage W2t (bf16 [48][128] -> [48][136]) + b1
    for (int i = tid; i < 48 * 128; i += 256)
        wt2s[(i >> 7) * 136 + (i & 127)] = W2t[i];
    if (tid < 128) b1s[tid] = b1[tid];
    if (tid < BNODES) ncnt[tid] = 0;
    __syncthreads();

    // ---- in-LDS counting sort of this bucket's edges ----
    int2 myrec[KSTG];
    if (fits) {
        #pragma unroll
        for (int k = 0; k < KSTG; k++) {
            int i = tid + k * 256;
            if (i < cnt) {
                int2 r = sortedA[beg + i];
                myrec[k] = r;
                atomicAdd(&ncnt[(r.x >> 17) & (BNODES - 1)], 1);
            }
        }
        __syncthreads();
        if (tid < BNODES) sc[tid] = ncnt[tid];
        __syncthreads();
        #pragma unroll
        for (int off = 1; off < BNODES; off <<= 1) {
            int u = (tid < BNODES && tid >= off) ? sc[tid - off] : 0;
            __syncthreads();
            if (tid < BNODES) sc[tid] += u;
            __syncthreads();
        }
        if (tid < BNODES) {
            int e0 = sc[tid] - ncnt[tid];
            nofs[tid] = e0;
            ncur[tid] = e0;
        }
        __syncthreads();
        #pragma unroll
        for (int k = 0; k < KSTG; k++) {
            int i = tid + k * 256;
            if (i < cnt) {
                int nd = (myrec[k].x >> 17) & (BNODES - 1);
                int p = atomicAdd(&ncur[nd], 1);
                ebuf[p] = myrec[k];
            }
        }
        __syncthreads();
    }

    // ---- barrier-free accumulate: group g owns nodes [8g, 8g+8) ----
    const int g = tid >> 5;
    const int lane = tid & 31;
    const unsigned short* hb = h1b + lane * 4;

    for (int ln = g * 8; ln < g * 8 + 8; ln++) {
        if (ln >= nn) break;
        float4 acc = {0.f, 0.f, 0.f, 0.f};
        if (fits) {
            const int s0 = nofs[ln];
            const int c0 = ncnt[ln];
            int j = 0;
            for (; j + 8 <= c0; j += 8) {
                int2 r[8];
                #pragma unroll
                for (int q = 0; q < 8; q++) r[q] = ebuf[s0 + j + q];
                ushort4 hv[8];
                #pragma unroll
                for (int q = 0; q < 8; q++)
                    hv[q] = *(const ushort4*)(hb + (size_t)(r[q].x & 0x1FFFF) * NHID);
                #pragma unroll
                for (int q = 0; q < 8; q++) {
                    float wj = __int_as_float(r[q].y);
                    acc.x = fmaf(wj, bf16_to_f32(hv[q].x), acc.x);
                    acc.y = fmaf(wj, bf16_to_f32(hv[q].y), acc.y);
                    acc.z = fmaf(wj, bf16_to_f32(hv[q].z), acc.z);
                    acc.w = fmaf(wj, bf16_to_f32(hv[q].w), acc.w);
                }
            }
            for (; j + 4 <= c0; j += 4) {
                int2 r[4];
                #pragma unroll
                for (int q = 0; q < 4; q++) r[q] = ebuf[s0 + j + q];
                ushort4 hv[4];
                #pragma unroll
                for (int q = 0; q < 4; q++)
                    hv[q] = *(const ushort4*)(hb + (size_t)(r[q].x & 0x1FFFF) * NHID);
                #pragma unroll
                for (int q = 0; q < 4; q++) {
                    float wj = __int_as_float(r[q].y);
                    acc.x = fmaf(wj, bf16_to_f32(hv[q].x), acc.x);
                    acc.y = fmaf(wj, bf16_to_f32(hv[q].y), acc.y);
                    acc.z = fmaf(wj, bf16_to_f32(hv[q].z), acc.z);
                    acc.w = fmaf(wj, bf16_to_f32(hv[q].w), acc.w);
                }
            }
            for (; j < c0; j++) {
                int2 r = ebuf[s0 + j];
                float wj = __int_as_float(r.y);
                ushort4 hv = *(const ushort4*)(hb + (size_t)(r.x & 0x1FFFF) * NHID);
                acc.x = fmaf(wj, bf16_to_f32(hv.x), acc.x);
                acc.y = fmaf(wj, bf16_to_f32(hv.y), acc.y);
                acc.z = fmaf(wj, bf16_to_f32(hv.z), acc.z);
                acc.w = fmaf(wj, bf16_to_f32(hv.w), acc.w);
            }
        } else {
            // fallback (never for this graph): filter-scan global range
            for (int e = beg; e < end; e++) {
                int2 r = sortedA[e];
                if (((r.x >> 17) & (BNODES - 1)) == ln) {
                    float wj = __int_as_float(r.y);
                    ushort4 hv = *(const ushort4*)(hb + (size_t)(r.x & 0x1FFFF) * NHID);
                    acc.x = fmaf(wj, bf16_to_f32(hv.x), acc.x);
                    acc.y = fmaf(wj, bf16_to_f32(hv.y), acc.y);
                    acc.z = fmaf(wj, bf16_to_f32(hv.z), acc.z);
                    acc.w = fmaf(wj, bf16_to_f32(hv.w), acc.w);
                }
            }
        }
        float4 bb = *(const float4*)&b1s[lane * 4];
        ushort4 px;
        px.x = f32_to_bf16(fmaxf(acc.x + bb.x, 0.f));
        px.y = f32_to_bf16(fmaxf(acc.y + bb.y, 0.f));
        px.z = f32_to_bf16(fmaxf(acc.z + bb.z, 0.f));
        px.w = f32_to_bf16(fmaxf(acc.w + bb.w, 0.f));
        *(ushort4*)&xs[ln][lane * 4] = px;
    }
    __syncthreads();

    // ---- MFMA gemm2: h2[64][40] = xs(bf16) @ W2t(bf16) ----
    const int wv = tid >> 6;            // wave: rows [wv*16, wv*16+16)
    const int l64 = tid & 63;
    const int lr = l64 & 15;
    const int quad = l64 >> 4;

    f32x4 c_[3];
    #pragma unroll
    for (int nt = 0; nt < 3; nt++)
        c_[nt] = (f32x4){0.f, 0.f, 0.f, 0.f};

    #pragma unroll
    for (int k0 = 0; k0 < 128; k0 += 32) {
        bf16x8 af = *(const bf16x8*)&xs[wv * 16 + lr][k0 + quad * 8];
        bf16x8 bf_[3];
        #pragma unroll
        for (int nt = 0; nt < 3; nt++)
            bf_[nt] = *(const bf16x8*)&wt2s[(nt * 16 + lr) * 136 + k0 + quad * 8];
        #pragma unroll
        for (int nt = 0; nt < 3; nt++)
            c_[nt] = __builtin_amdgcn_mfma_f32_16x16x32_bf16(
                af, bf_[nt], c_[nt], 0, 0, 0);
    }

    #pragma unroll
    for (int nt = 0; nt < 3; nt++) {
        int col = nt * 16 + lr;
        if (col < NCLASS) {
            #pragma unroll
            for (int i = 0; i < 4; i++) {
                int row = wv * 16 + quad * 4 + i;
                if (row < nn)
                    h2[(size_t)(node0 + row) * NCLASS + col] = c_[nt][i];
            }
        }
    }
}

// ---------------------------------------------------------------------------
// agg2 + bias + log_softmax: one block per 64-node bucket; in-LDS counting
// sort; 16 groups x 16 lanes, 4 iterations of 16 nodes.
// ---------------------------------------------------------------------------
__global__ __launch_bounds__(256) void agg2_softmax_kernel(
    const int2* __restrict__ sortedA, const int* __restrict__ bofs,
    const float* __restrict__ h2, const float* __restrict__ b2,
    float* __restrict__ out, int N)
{
    __shared__ __align__(16) int2 ebuf[CAP];     // 12,288 B
    __shared__ int ncnt[BNODES];
    __shared__ int nofs[BNODES];
    __shared__ int ncur[BNODES];
    __shared__ int sc[BNODES];

    const int tid = threadIdx.x;
    const int b = blockIdx.x;
    const int node0 = b << BSH;
    const int nn = min(BNODES, N - node0);
    const int beg = bofs[b];
    const int end = bofs[b + 1];
    const int cnt = end - beg;
    const bool fits = (cnt <= CAP);

    if (tid < BNODES) ncnt[tid] = 0;
    __syncthreads();

    int2 myrec[KSTG];
    if (fits) {
        #pragma unroll
        for (int k = 0; k < KSTG; k++) {
            int i = tid + k * 256;
            if (i < cnt) {
                int2 r = sortedA[beg + i];
                myrec[k] = r;
                atomicAdd(&ncnt[(r.x >> 17) & (BNODES - 1)], 1);
            }
        }
        __syncthreads();
        if (tid < BNODES) sc[tid] = ncnt[tid];
        __syncthreads();
        #pragma unroll
        for (int off = 1; off < BNODES; off <<= 1) {
            int u = (tid < BNODES && tid >= off) ? sc[tid - off] : 0;
            __syncthreads();
            if (tid < BNODES) sc[tid] += u;
            __syncthreads();
        }
        if (tid < BNODES) {
            int e0 = sc[tid] - ncnt[tid];
            nofs[tid] = e0;
            ncur[tid] = e0;
        }
        __syncthreads();
        #pragma unroll
        for (int k = 0; k < KSTG; k++) {
            int i = tid + k * 256;
            if (i < cnt) {
                int nd = (myrec[k].x >> 17) & (BNODES - 1);
                int p = atomicAdd(&ncur[nd], 1);
                ebuf[p] = myrec[k];
            }
        }
        __syncthreads();
    }

    const int grp = tid >> 4;     // 0..15
    const int l16 = tid & 15;
    const float* hp0 = h2 + l16 * 4;

    for (int it = 0; it < 4; it++) {
        const int ln = it * 16 + grp;
        float4 acc = {0.f, 0.f, 0.f, 0.f};
        if (ln < nn) {
            if (fits) {
                const int s0 = nofs[ln];
                const int c0 = ncnt[ln];
                int j = 0;
                for (; j + 8 <= c0; j += 8) {
                    int2 r[8];
                    #pragma unroll
                    for (int q = 0; q < 8; q++) r[q] = ebuf[s0 + j + q];
                    if (l16 < 10) {
                        float4 v[8];
                        #pragma unroll
                        for (int q = 0; q < 8; q++)
                            v[q] = *(const float4*)(hp0 + (size_t)(r[q].x & 0x1FFFF) * NCLASS);
                        #pragma unroll
                        for (int q = 0; q < 8; q++) {
                            float wj = __int_as_float(r[q].y);
                            acc.x = fmaf(wj, v[q].x, acc.x);
                            acc.y = fmaf(wj, v[q].y, acc.y);
                            acc.z = fmaf(wj, v[q].z, acc.z);
                            acc.w = fmaf(wj, v[q].w, acc.w);
                        }
                    }
                }
                for (; j + 4 <= c0; j += 4) {
                    int2 r[4];
                    #pragma unroll
                    for (int q = 0; q < 4; q++) r[q] = ebuf[s0 + j + q];
                    if (l16 < 10) {
                        float4 v[4];
                        #pragma unroll
                        for (int q = 0; q < 4; q++)
                            v[q] = *(const float4*)(hp0 + (size_t)(r[q].x & 0x1FFFF) * NCLASS);
                        #pragma unroll
                        for (int q = 0; q < 4; q++) {
                            float wj = __int_as_float(r[q].y);
                            acc.x = fmaf(wj, v[q].x, acc.x);
                            acc.y = fmaf(wj, v[q].y, acc.y);
                            acc.z = fmaf(wj, v[q].z, acc.z);
                            acc.w = fmaf(wj, v[q].w, acc.w);
                        }
                    }
                }
                for (; j < c0; j++) {
                    int2 r = ebuf[s0 + j];
                    if (l16 < 10) {
                        float wj = __int_as_float(r.y);
                        float4 v = *(const float4*)(hp0 + (size_t)(r.x & 0x1FFFF) * NCLASS);
                        acc.x = fmaf(wj, v.x, acc.x);
                        acc.y = fmaf(wj, v.y, acc.y);
                        acc.z = fmaf(wj, v.z, acc.z);
                        acc.w = fmaf(wj, v.w, acc.w);
                    }
                }
            } else {
                for (int e = beg; e < end; e++) {
                    int2 r = sortedA[e];
                    if (((r.x >> 17) & (BNODES - 1)) == ln && l16 < 10) {
                        float wj = __int_as_float(r.y);
                        float4 v = *(const float4*)(hp0 + (size_t)(r.x & 0x1FFFF) * NCLASS);
                        acc.x = fmaf(wj, v.x, acc.x);
                        acc.y = fmaf(wj, v.y, acc.y);
                        acc.z = fmaf(wj, v.z, acc.z);
                        acc.w = fmaf(wj, v.w, acc.w);
                    }
                }
            }
        }
        // bias + log_softmax (16-lane groups; lanes 0..9 hold 40 values)
        bool act = (ln < nn) && (l16 < 10);
        float mx = -INFINITY;
        if (act) {
            float4 bb = *(const float4*)&b2[l16 * 4];
            acc.x += bb.x; acc.y += bb.y; acc.z += bb.z; acc.w += bb.w;
            mx = fmaxf(fmaxf(acc.x, acc.y), fmaxf(acc.z, acc.w));
        }
        #pragma unroll
        for (int o = 8; o > 0; o >>= 1) mx = fmaxf(mx, __shfl_xor(mx, o, 16));
        float sm = act ? expf(acc.x - mx) + expf(acc.y - mx) +
                         expf(acc.z - mx) + expf(acc.w - mx) : 0.f;
        #pragma unroll
        for (int o = 8; o > 0; o >>= 1) sm += __shfl_xor(sm, o, 16);
        if (act) {
            float l = mx + logf(sm);
            float4 o4 = {acc.x - l, acc.y - l, acc.z - l, acc.w - l};
            *(float4*)&out[(size_t)(node0 + ln) * NCLASS + l16 * 4] = o4;
        }
    }
}

extern "C" void kernel_launch(void* const* d_in, const int* in_sizes, int n_in,
                              void* d_out, int out_size, void* d_ws, size_t ws_size,
                              hipStream_t stream) {
    const float* features = (const float*)d_in[0];
    const int* edge_src   = (const int*)d_in[1];
    const int* edge_dst   = (const int*)d_in[2];
    const float* edge_w   = (const float*)d_in[3];
    const float* W1       = (const float*)d_in[4];
    const float* b1       = (const float*)d_in[5];
    const float* W2       = (const float*)d_in[6];
    const float* b2       = (const float*)d_in[7];
    float* out = (float*)d_out;

    // Workspace layout (bytes from base):
    //   h2:      fp32 [N,40]            @ 0          (16,000,000)
    //   h1b:     bf16 [N,128]           @ 51,200,000 (25,600,000)
    //   Wt:      bf16 [128,512]         @ 76,800,000 (131,072)
    //   histG:   int  [NBUCK*16]        @ 76,931,072 (100,032; 64B-padded)
    //   bofs:    int  [NBUCK+1]         @ 77,040,000 (6,256)
    //   bcursor: int  [NBUCK]           @ 77,050,000 (6,252)
    //   W2t:     bf16 [48,128]          @ 77,060,000 (12,288)
    //   sortedA: int2 [E]               @ 90,540,000 (12,800,000)
    char* base = (char*)d_ws;
    float*          h2       = (float*)base;
    unsigned short* h1b      = (unsigned short*)(base + 51200000);
    unsigned short* Wt       = (unsigned short*)(base + 76800000);
    int*            histG    = (int*)(base + 76931072);
    int*            bofs     = (int*)(base + 77040000);
    int*            bcursor  = (int*)(base + 77050000);
    unsigned short* W2t      = (unsigned short*)(base + 77060000);
    int2*           sortedA  = (int2*)(base + 90540000);

    hipMemsetAsync(histG, 0, NBUCK * 16 * sizeof(int), stream);

    // bucket hist + W1/W2 transpose fused (W2t: 24 tail blocks)
    bucket_hist_transpose_kernel<<<PNB + 256 + 24, 256, 0, stream>>>(
        edge_dst, histG, W1, Wt, W2, W2t, N_EDGES);
    bucket_scan_kernel<<<1, 1024, 0, stream>>>(histG, bofs, bcursor);

    // partition (grouped write-out)
    partition_kernel<<<PNB, 256, 0, stream>>>(
        edge_src, edge_dst, edge_w, bcursor, sortedA, N_EDGES);

    // Dense layer 1: bf16 MFMA
    gemm1_mfma_kernel<<<(N_NODES + 127) / 128, 256, 0, stream>>>(
        features, Wt, h1b, N_NODES);

    // Aggregate 1 + bias + relu + dense layer 2 (barrier-free + MFMA epilogue)
    agg1_gemm2_kernel<<<NBUCK, 256, 0, stream>>>(
        sortedA, bofs, h1b, b1, W2t, h2, N_NODES);

    // Aggregate 2 + bias + log_softmax (in-LDS counting sort)
    agg2_softmax_kernel<<<NBUCK, 256, 0, stream>>>(
        sortedA, bofs, h2, b2, out, N_NODES);
}